// Round 1
// baseline (1150.397 us; speedup 1.0000x reference)
//
#include <hip/hip_runtime.h>

#define D_    256
#define V_    32
#define HW_   (512*512)
#define OUTF_ 256

// ---------------------------------------------------------------------------
// K1: per-pixel Q logits + softmax. Q[p,i] = sum_d ((x_pd - W_di)*iv_di)^2
// computed as e = fmaf(x, iv, -(W*iv)); q += e*e  (no cancellation, no bias).
// A=W*iv, B=iv staged in LDS (exactly 64KB -> 2 blocks/CU).
// 2 pixels per thread to amortize LDS broadcast reads.
// Also accumulates s[i] = sum_p Q[p,i] via LDS (reused from A) + global atomics.
// ---------------------------------------------------------------------------
__global__ __launch_bounds__(256) void k1_q(const float* __restrict__ X,
                                            const float* __restrict__ W,
                                            const float* __restrict__ var,
                                            float* __restrict__ Q,
                                            float* __restrict__ s_out)
{
    __shared__ float As[D_][V_];   // W * iv
    __shared__ float Bs[D_][V_];   // iv
    const int tid = threadIdx.x;

    // setup: thread t = row d
    {
        const float* wr = W   + tid * V_;
        const float* vr = var + tid * V_;
        #pragma unroll
        for (int i = 0; i < V_; ++i) {
            float iv = 1.0f / vr[i];
            As[tid][i] = wr[i] * iv;
            Bs[tid][i] = iv;
        }
    }
    __syncthreads();

    const size_t pA = (size_t)blockIdx.x * 512 + tid;
    const size_t pB = pA + 256;
    const float4* xrowA = (const float4*)(X + pA * D_);
    const float4* xrowB = (const float4*)(X + pB * D_);

    float tA[V_], tB[V_];
    #pragma unroll
    for (int i = 0; i < V_; ++i) { tA[i] = 0.f; tB[i] = 0.f; }

    for (int d4 = 0; d4 < D_/4; ++d4) {
        float4 xa = xrowA[d4];
        float4 xb = xrowB[d4];
        float xsa[4] = {xa.x, xa.y, xa.z, xa.w};
        float xsb[4] = {xb.x, xb.y, xb.z, xb.w};
        #pragma unroll
        for (int k = 0; k < 4; ++k) {
            const int d = d4*4 + k;
            const float xA = xsa[k];
            const float xB = xsb[k];
            #pragma unroll
            for (int i = 0; i < V_; ++i) {
                const float bi = Bs[d][i];
                const float ai = As[d][i];
                float eA = fmaf(xA, bi, -ai);
                float eB = fmaf(xB, bi, -ai);
                tA[i] = fmaf(eA, eA, tA[i]);
                tB[i] = fmaf(eB, eB, tB[i]);
            }
        }
    }

    // softmax for both pixels, write Q rows
    float qA[V_], qB[V_];
    float mnA = 3.4e38f, mnB = 3.4e38f;
    #pragma unroll
    for (int i = 0; i < V_; ++i) { mnA = fminf(mnA, tA[i]); mnB = fminf(mnB, tB[i]); }
    float sumA = 0.f, sumB = 0.f;
    #pragma unroll
    for (int i = 0; i < V_; ++i) {
        qA[i] = __expf(-0.5f * (tA[i] - mnA));  sumA += qA[i];
        qB[i] = __expf(-0.5f * (tB[i] - mnB));  sumB += qB[i];
    }
    const float invA = 1.0f / sumA;
    const float invB = 1.0f / sumB;

    float4* qoutA = (float4*)(Q + pA * V_);
    float4* qoutB = (float4*)(Q + pB * V_);
    #pragma unroll
    for (int j = 0; j < V_/4; ++j) {
        float4 oa, ob;
        oa.x = qA[4*j+0]*invA; oa.y = qA[4*j+1]*invA; oa.z = qA[4*j+2]*invA; oa.w = qA[4*j+3]*invA;
        ob.x = qB[4*j+0]*invB; ob.y = qB[4*j+1]*invB; ob.z = qB[4*j+2]*invB; ob.w = qB[4*j+3]*invB;
        qoutA[j] = oa;
        qoutB[j] = ob;
    }

    // s accumulation: reuse As storage as a 32-float block accumulator
    __syncthreads();               // everyone done reading As/Bs
    float* s_blk = &As[0][0];
    if (tid < V_) s_blk[tid] = 0.f;
    __syncthreads();
    #pragma unroll
    for (int i = 0; i < V_; ++i) {
        atomicAdd(&s_blk[i], qA[i]*invA + qB[i]*invB);
    }
    __syncthreads();
    if (tid < V_) atomicAdd(&s_out[tid], s_blk[tid]);
}

// ---------------------------------------------------------------------------
// K2: M[d,i] = sum_p X[p,d] * Q[p,i].  thread <-> d; 512 pixels per block;
// x loads coalesced, q row is wave-uniform (broadcast/scalar); one atomic
// flush of 32 values per thread at the end.
// ---------------------------------------------------------------------------
__global__ __launch_bounds__(256) void k2_m(const float* __restrict__ X,
                                            const float* __restrict__ Q,
                                            float* __restrict__ M)
{
    const int d = threadIdx.x;
    const size_t p0 = (size_t)blockIdx.x * 512;
    float acc[V_];
    #pragma unroll
    for (int i = 0; i < V_; ++i) acc[i] = 0.f;

    for (int pp = 0; pp < 512; ++pp) {
        const size_t p = p0 + pp;
        const float x = X[p * D_ + d];
        const float* qr = Q + p * V_;
        #pragma unroll
        for (int i = 0; i < V_; ++i) acc[i] = fmaf(x, qr[i], acc[i]);
    }
    #pragma unroll
    for (int i = 0; i < V_; ++i) atomicAdd(&M[d*V_ + i], acc[i]);
}

// ---------------------------------------------------------------------------
// K3a: Z = (M - W*s)*iv/s ; Z /= sum_d Z^2 (per column) ; Adj = Z^T Z
// single block, 256 threads (thread = d).
// ---------------------------------------------------------------------------
__global__ __launch_bounds__(256) void k3a(const float* __restrict__ M,
                                           const float* __restrict__ s_in,
                                           const float* __restrict__ W,
                                           const float* __restrict__ var,
                                           float* __restrict__ Z,
                                           float* __restrict__ Adj)
{
    __shared__ float Zl[D_][V_];
    __shared__ float ss[V_];
    __shared__ float nrm[V_];
    const int t = threadIdx.x;
    if (t < V_) ss[t] = s_in[t];
    __syncthreads();

    #pragma unroll
    for (int i = 0; i < V_; ++i) {
        float iv = 1.0f / var[t*V_ + i];
        float z = (M[t*V_ + i] - W[t*V_ + i] * ss[i]) * iv / ss[i];
        Zl[t][i] = z;
    }
    __syncthreads();
    if (t < V_) {
        float n = 0.f;
        for (int d = 0; d < D_; ++d) { float z = Zl[d][t]; n = fmaf(z, z, n); }
        nrm[t] = n;
    }
    __syncthreads();
    #pragma unroll
    for (int i = 0; i < V_; ++i) {
        float z = Zl[t][i] / nrm[i];
        Zl[t][i] = z;
        Z[t*V_ + i] = z;
    }
    __syncthreads();
    // Adj: 1024 entries, 4 per thread
    #pragma unroll
    for (int e = 0; e < 4; ++e) {
        int idx = t*4 + e;
        int i = idx >> 5, j = idx & 31;
        float a = 0.f;
        for (int d = 0; d < D_; ++d) a = fmaf(Zl[d][i], Zl[d][j], a);
        Adj[idx] = a;
    }
}

// ---------------------------------------------------------------------------
// K3b: T[j] = sum_d Z[d,j]*weight[d,f] ; Zo[i,f] = relu(sum_j Adj[i,j]*T[j])
// one block per output column f.
// ---------------------------------------------------------------------------
__global__ __launch_bounds__(256) void k3b(const float* __restrict__ Z,
                                           const float* __restrict__ weight,
                                           const float* __restrict__ Adj,
                                           float* __restrict__ Zo)
{
    __shared__ float T[V_];
    const int t = threadIdx.x;
    const int f = blockIdx.x;
    if (t < V_) T[t] = 0.f;
    __syncthreads();
    const float wt = weight[t*OUTF_ + f];
    const float* zr = Z + t*V_;
    #pragma unroll
    for (int j = 0; j < V_; ++j) atomicAdd(&T[j], zr[j] * wt);
    __syncthreads();
    if (t < V_) {
        float o = 0.f;
        #pragma unroll
        for (int j = 0; j < V_; ++j) o = fmaf(Adj[t*V_ + j], T[j], o);
        Zo[t*OUTF_ + f] = fmaxf(o, 0.f);
    }
}

// ---------------------------------------------------------------------------
// K4: out[p,f] = sum_i Q[p,i] * Zo[i,f].  thread <-> f (Zo column in regs,
// loaded coalesced); Q tile staged in LDS, broadcast reads; coalesced stores.
// ---------------------------------------------------------------------------
__global__ __launch_bounds__(256) void k4_out(const float* __restrict__ Q,
                                              const float* __restrict__ Zo,
                                              float* __restrict__ out)
{
    __shared__ float Qt[256][V_];
    const int t = threadIdx.x;
    const size_t p0 = (size_t)blockIdx.x * 256;

    float zc[V_];
    #pragma unroll
    for (int i = 0; i < V_; ++i) zc[i] = Zo[i*OUTF_ + t];

    {
        float4* dst = (float4*)(&Qt[t][0]);
        const float4* src = (const float4*)(Q + (p0 + t) * V_);
        #pragma unroll
        for (int j = 0; j < V_/4; ++j) dst[j] = src[j];
    }
    __syncthreads();

    #pragma unroll 2
    for (int p = 0; p < 256; ++p) {
        float a0 = 0.f, a1 = 0.f, a2 = 0.f, a3 = 0.f;
        #pragma unroll
        for (int i = 0; i < V_; i += 4) {
            a0 = fmaf(Qt[p][i+0], zc[i+0], a0);
            a1 = fmaf(Qt[p][i+1], zc[i+1], a1);
            a2 = fmaf(Qt[p][i+2], zc[i+2], a2);
            a3 = fmaf(Qt[p][i+3], zc[i+3], a3);
        }
        out[(p0 + p) * OUTF_ + t] = (a0 + a1) + (a2 + a3);
    }
}

extern "C" void kernel_launch(void* const* d_in, const int* in_sizes, int n_in,
                              void* d_out, int out_size, void* d_ws, size_t ws_size,
                              hipStream_t stream)
{
    const float* X      = (const float*)d_in[0];
    const float* W      = (const float*)d_in[1];
    const float* var    = (const float*)d_in[2];
    const float* weight = (const float*)d_in[3];
    float* out = (float*)d_out;
    float* ws  = (float*)d_ws;

    float* Q   = ws;                         // HW_*V_ floats (32 MB)
    float* s   = Q   + (size_t)HW_ * V_;     // 32
    float* M   = s   + V_;                   // D_*V_
    float* Z   = M   + D_ * V_;              // D_*V_
    float* Adj = Z   + D_ * V_;              // V_*V_
    float* Zo  = Adj + V_ * V_;              // V_*OUTF_

    // zero the atomic accumulators (s and M are contiguous)
    hipMemsetAsync(s, 0, (V_ + D_*V_) * sizeof(float), stream);

    k1_q <<<HW_/512, 256, 0, stream>>>(X, W, var, Q, s);
    k2_m <<<HW_/512, 256, 0, stream>>>(X, Q, M);
    k3a  <<<1,       256, 0, stream>>>(M, s, W, var, Z, Adj);
    k3b  <<<OUTF_,   256, 0, stream>>>(Z, weight, Adj, Zo);
    k4_out<<<HW_/256, 256, 0, stream>>>(Q, Zo, out);
}